// Round 2
// baseline (2303.838 us; speedup 1.0000x reference)
//
#include <hip/hip_runtime.h>
#include <hip/hip_bf16.h>

#define HID    256
#define AFD    133
#define KA_PAD 160
#define KB_PAD 32
#define MAXNB  16
#define BN_EPS 1e-5f

typedef __attribute__((ext_vector_type(8))) __bf16 bf16x8;
typedef __attribute__((ext_vector_type(4))) float  f32x4;

__device__ __forceinline__ unsigned short f2bf(float x){
  union { __hip_bfloat16 b; unsigned short u; } cv;
  cv.b = __float2bfloat16(x);
  return cv.u;
}
__device__ __forceinline__ float bf2f(unsigned short u){
  union { unsigned int i; float f; } cv;
  cv.i = ((unsigned int)u) << 16;
  return cv.f;
}

// XOR swizzle on 16B blocks within a row-stripe: kills ds_read_b128 bank conflicts
__device__ __forceinline__ unsigned swzb(int row, int kbyte, int rowStrideB){
  return (unsigned)(row*rowStrideB + kbyte) ^ (unsigned)((row & 7) << 4);
}

__device__ __forceinline__ f32x4 mfma16(bf16x8 a, bf16x8 b, f32x4 c){
  return __builtin_amdgcn_mfma_f32_16x16x32_bf16(a, b, c, 0, 0, 0);
}

// ---------------- packing kernels ----------------

__global__ void pack_wT(const float* __restrict__ W, unsigned short* __restrict__ WT,
                        int K, int Ncols, int Kpad){
  int total = Ncols * Kpad;
  for(int idx = blockIdx.x*blockDim.x + threadIdx.x; idx < total; idx += gridDim.x*blockDim.x){
    int col = idx / Kpad, k = idx - col*Kpad;
    float v = (k < K) ? W[(size_t)k*Ncols + col] : 0.f;
    WT[idx] = f2bf(v);
  }
}

__global__ void pack_eb(const float* __restrict__ fb, unsigned short* __restrict__ eb, int E){
  int total = E*16;
  for(int idx = blockIdx.x*blockDim.x + threadIdx.x; idx < total; idx += gridDim.x*blockDim.x){
    int e = idx >> 4, k = idx & 15;
    float v = (k < 15) ? fb[(size_t)e*15 + k] : 0.f;
    eb[idx] = f2bf(v);
  }
}

// covered[b]=1 for every bond that appears in a2b (those route to their atom;
// uncovered bonds route to atom 0 in the reference, handled by leftover0)
__global__ void build_cov(const int* __restrict__ a2b, unsigned char* __restrict__ cov, int N){
  int total = N*MAXNB;
  for(int idx = blockIdx.x*blockDim.x + threadIdx.x; idx < total; idx += gridDim.x*blockDim.x){
    int b = a2b[idx];
    if(b > 0) cov[b] = 1;
  }
}

// self-loop embedding per layer
__global__ void sl_emb_kernel(const float* __restrict__ w1, const float* __restrict__ b1,
                              const float* __restrict__ w2, const float* __restrict__ b2,
                              float* __restrict__ sl){
  int l = blockIdx.x, t = threadIdx.x;
  __shared__ float hid[HID];
  float hv = w1[((size_t)l*16 + 15)*HID + t] + b1[(size_t)l*HID + t];
  hid[t] = hv > 0.f ? hv : 0.f;
  __syncthreads();
  const float* W2 = w2 + (size_t)l*HID*HID;
  float acc = b2[(size_t)l*HID + t];
  for(int k=0;k<HID;k++) acc += hid[k] * W2[(size_t)k*HID + t];
  sl[(size_t)l*HID + t] = acc;
}

// ---------------- h0 = f_atoms @ w_atom ----------------

__global__ __launch_bounds__(256,2) void atom_embed(
    const float* __restrict__ fat, const unsigned short* __restrict__ wAT,
    float* __restrict__ h, int N)
{
  __shared__ alignas(16) unsigned short sA[64*KA_PAD];
  const int t = threadIdx.x;
  const int m0 = blockIdx.x*64;
  for(int i=t; i<64*KA_PAD; i+=256){
    int row = i / KA_PAD;
    int k   = i - row*KA_PAD;
    int gr  = m0 + row;
    float v = (gr < N && k < AFD) ? fat[(size_t)gr*AFD + k] : 0.f;
    *(unsigned short*)((char*)sA + swzb(row, k*2, KA_PAD*2)) = f2bf(v);
  }
  __syncthreads();
  const int w = t>>6, l = t&63, lg = l>>4, lc = l&15;
  const f32x4 z4 = {0.f,0.f,0.f,0.f};
  f32x4 acc[4][4];
#pragma unroll
  for(int fi=0;fi<4;fi++)
#pragma unroll
    for(int fj=0;fj<4;fj++) acc[fi][fj] = z4;
  for(int k0=0;k0<KA_PAD;k0+=32){
    bf16x8 a[4], b[4];
#pragma unroll
    for(int fi=0;fi<4;fi++)
      a[fi] = *(const bf16x8*)((const char*)sA + swzb(fi*16+lc, (k0+lg*8)*2, KA_PAD*2));
#pragma unroll
    for(int fj=0;fj<4;fj++){
      int col = w*64 + fj*16 + lc;
      b[fj] = *(const bf16x8*)(wAT + (size_t)col*KA_PAD + k0 + lg*8);
    }
#pragma unroll
    for(int fi=0;fi<4;fi++)
#pragma unroll
      for(int fj=0;fj<4;fj++)
        acc[fi][fj] = mfma16(a[fi], b[fj], acc[fi][fj]);
  }
#pragma unroll
  for(int fj=0;fj<4;fj++){
    int col = w*64 + fj*16 + lc;
#pragma unroll
    for(int fi=0;fi<4;fi++)
#pragma unroll
      for(int r=0;r<4;r++){
        int gr = m0 + fi*16 + lg*4 + r;
        if(gr < N) h[(size_t)gr*HID + col] = acc[fi][fj][r];
      }
  }
}

// ---------------- edge MLP -> msg (bf16 rows, no atomics) ----------------

__global__ __launch_bounds__(256,2) void edge_mlp_msg(
    const unsigned short* __restrict__ eb,
    const unsigned short* __restrict__ w1T, const float* __restrict__ b1,
    const unsigned short* __restrict__ w2T, const float* __restrict__ b2,
    const int* __restrict__ b2a,
    const float* __restrict__ hraw,
    const float* __restrict__ musig, const float* __restrict__ gamma,
    const float* __restrict__ beta, int applyBN,
    unsigned short* __restrict__ msg, int E)
{
  __shared__ alignas(16) unsigned short sEB[64*32];
  __shared__ alignas(16) unsigned short sH[64*256];
  __shared__ int sB2A[64];
  const int t  = threadIdx.x;
  const int e0 = blockIdx.x*64;
  {
    int row = t >> 2;
    int kc  = (t & 3) << 3;
    uint4 val = make_uint4(0,0,0,0);
    int e = e0 + row;
    if(kc < 16 && e < E) val = *(const uint4*)(eb + (size_t)e*16 + kc);
    *(uint4*)((char*)sEB + swzb(row, kc*2, 64)) = val;
  }
  if(t < 64){
    int e = e0 + t;
    sB2A[t] = (e < E) ? b2a[e] : 0;
  }
  __syncthreads();

  const int w = t>>6, l = t&63, lg = l>>4, lc = l&15;
  const f32x4 z4 = {0.f,0.f,0.f,0.f};

  { // stage 1: hid1 = relu(eb @ w1 + b1) -> sH (bf16)
    bf16x8 a[4], b[4];
#pragma unroll
    for(int fi=0;fi<4;fi++)
      a[fi] = *(const bf16x8*)((const char*)sEB + swzb(fi*16+lc, lg*16, 64));
#pragma unroll
    for(int fj=0;fj<4;fj++){
      int col = w*64 + fj*16 + lc;
      b[fj] = *(const bf16x8*)(w1T + (size_t)col*KB_PAD + lg*8);
    }
    f32x4 s1[4][4];
#pragma unroll
    for(int fi=0;fi<4;fi++)
#pragma unroll
      for(int fj=0;fj<4;fj++)
        s1[fi][fj] = mfma16(a[fi], b[fj], z4);
#pragma unroll
    for(int fj=0;fj<4;fj++){
      int col = w*64 + fj*16 + lc;
      float bias = b1[col];
#pragma unroll
      for(int fi=0;fi<4;fi++)
#pragma unroll
        for(int r=0;r<4;r++){
          int row = fi*16 + lg*4 + r;
          float v = s1[fi][fj][r] + bias;
          v = v > 0.f ? v : 0.f;
          *(unsigned short*)((char*)sH + swzb(row, col*2, 512)) = f2bf(v);
        }
    }
  }
  __syncthreads();

  // stage 2: e_emb = hid1 @ w2
  f32x4 acc[4][4];
#pragma unroll
  for(int fi=0;fi<4;fi++)
#pragma unroll
    for(int fj=0;fj<4;fj++) acc[fi][fj] = z4;
  for(int k0=0;k0<256;k0+=32){
    bf16x8 a[4], b[4];
#pragma unroll
    for(int fi=0;fi<4;fi++)
      a[fi] = *(const bf16x8*)((const char*)sH + swzb(fi*16+lc, (k0+lg*8)*2, 512));
#pragma unroll
    for(int fj=0;fj<4;fj++){
      int col = w*64 + fj*16 + lc;
      b[fj] = *(const bf16x8*)(w2T + (size_t)col*256 + k0 + lg*8);
    }
#pragma unroll
    for(int fi=0;fi<4;fi++)
#pragma unroll
      for(int fj=0;fj<4;fj++)
        acc[fi][fj] = mfma16(a[fi], b[fj], acc[fi][fj]);
  }
  __syncthreads();   // all waves done reading sH; about to overwrite

  // epilogue: msg = e_emb + b2 + BNprev(h[b2a]) -> sH (bf16) -> global
  float bb[4], g4[4], mu4[4], rs4[4], be4[4];
#pragma unroll
  for(int fj=0;fj<4;fj++){
    int col = w*64 + fj*16 + lc;
    bb[fj] = b2[col];
    if(applyBN){
      g4[fj] = gamma[col]; mu4[fj] = musig[col];
      rs4[fj] = musig[256+col]; be4[fj] = beta[col];
    }
  }
#pragma unroll
  for(int fi=0;fi<4;fi++){
#pragma unroll
    for(int r=0;r<4;r++){
      int row = fi*16 + lg*4 + r;
      const float* hp = hraw + (size_t)sB2A[row]*HID;
#pragma unroll
      for(int fj=0;fj<4;fj++){
        int col = w*64 + fj*16 + lc;
        float hv = hp[col];
        if(applyBN){
          hv = g4[fj]*(hv - mu4[fj])*rs4[fj] + be4[fj];
          hv = hv > 0.f ? hv : 0.f;
        }
        float v = acc[fi][fj][r] + bb[fj] + hv;
        *(unsigned short*)((char*)sH + swzb(row, col*2, 512)) = f2bf(v);
      }
    }
  }
  __syncthreads();
  // coalesced copy out: 64 rows x 512B
  for(int c=t; c<2048; c+=256){
    int row = c >> 5;
    int off = (c & 31) << 4;
    int e = e0 + row;
    if(e < E){
      uint4 v = *(const uint4*)((const char*)sH + swzb(row, off, 512));
      ((uint4*)(msg + (size_t)e*256))[c & 31] = v;
    }
  }
}

// sum msg over uncovered bonds into leftover[256] (these route to atom 0)
__global__ void leftover0(const unsigned short* __restrict__ msg,
                          const unsigned char* __restrict__ cov,
                          float* __restrict__ lo, int E)
{
  int gw   = (blockIdx.x*blockDim.x + threadIdx.x) >> 6;
  int lane = threadIdx.x & 63;
  int nw   = (gridDim.x*blockDim.x) >> 6;
  for(int e = gw; e < E; e += nw){
    if(!cov[e]){
#pragma unroll
      for(int q=0;q<4;q++){
        int col = q*64 + lane;
        atomicAdd(&lo[col], bf2f(msg[(size_t)e*256 + col]));
      }
    }
  }
}

// ---------------- fused gather + node MLP + BN stats ----------------

__global__ __launch_bounds__(256,2) void node_mlp_fused(
    const unsigned short* __restrict__ msg,
    const int* __restrict__ a2b,
    const float* __restrict__ hraw, const float* __restrict__ sl,
    const float* __restrict__ lo,
    const float* __restrict__ musig, const float* __restrict__ gamma,
    const float* __restrict__ beta, int applyBN,
    const unsigned short* __restrict__ m1T, const float* __restrict__ b1,
    const unsigned short* __restrict__ m2T, const float* __restrict__ b2,
    float* __restrict__ z, float* __restrict__ stats, int N)
{
  __shared__ alignas(16) unsigned short sA [64*256];
  __shared__ alignas(16) unsigned short sHD[64*128];
  const int t  = threadIdx.x;
  const int m0 = blockIdx.x*64;

  // staging: aggr_row = BNprev(hraw) + sl + sum_{j} msg[a2b[row][j]] (+ leftover at atom 0)
  for(int p=0;p<2;p++){
    int row = p*32 + (t>>3);
    int gr  = m0 + row;
    int c0  = (t&7)*32;
    float acc[32];
    if(gr < N){
      const float* hp = hraw + (size_t)gr*HID + c0;
#pragma unroll
      for(int k=0;k<8;k++){
        float4 v = *(const float4*)(hp + k*4);
        acc[k*4+0]=v.x; acc[k*4+1]=v.y; acc[k*4+2]=v.z; acc[k*4+3]=v.w;
      }
      if(applyBN){
#pragma unroll
        for(int k=0;k<32;k++){
          int c = c0 + k;
          float x = gamma[c]*(acc[k] - musig[c])*musig[256+c] + beta[c];
          acc[k] = x > 0.f ? x : 0.f;
        }
      }
#pragma unroll
      for(int k=0;k<32;k++) acc[k] += sl[c0+k];
      if(gr == 0){
#pragma unroll
        for(int k=0;k<32;k++) acc[k] += lo[c0+k];
      }
      const int* ab = a2b + (size_t)gr*MAXNB;
      for(int j=0;j<MAXNB;j++){
        int b = ab[j];
        if(b == 0) break;
        const unsigned short* mp = msg + (size_t)b*HID + c0;
#pragma unroll
        for(int q=0;q<4;q++){
          union { uint4 v; unsigned short us[8]; } mv;
          mv.v = *(const uint4*)(mp + q*8);
#pragma unroll
          for(int x=0;x<8;x++) acc[q*8+x] += bf2f(mv.us[x]);
        }
      }
    } else {
#pragma unroll
      for(int k=0;k<32;k++) acc[k] = 0.f;
    }
#pragma unroll
    for(int q=0;q<4;q++){
      union { uint4 v; unsigned short us[8]; } pk;
#pragma unroll
      for(int x=0;x<8;x++) pk.us[x] = f2bf(acc[q*8+x]);
      *(uint4*)((char*)sA + swzb(row, (c0+q*8)*2, 512)) = pk.v;
    }
  }
  __syncthreads();

  const int w = t>>6, l = t&63, lg = l>>4, lc = l&15;
  const f32x4 z4 = {0.f,0.f,0.f,0.f};
  f32x4 zacc[4][4];
#pragma unroll
  for(int fi=0;fi<4;fi++)
#pragma unroll
    for(int fj=0;fj<4;fj++) zacc[fi][fj] = z4;

  for(int c=0;c<4;c++){
    f32x4 h1[4][2];
#pragma unroll
    for(int fi=0;fi<4;fi++){ h1[fi][0] = z4; h1[fi][1] = z4; }
    for(int k0=0;k0<256;k0+=32){
      bf16x8 a[4];
#pragma unroll
      for(int fi=0;fi<4;fi++)
        a[fi] = *(const bf16x8*)((const char*)sA + swzb(fi*16+lc, (k0+lg*8)*2, 512));
#pragma unroll
      for(int fj=0;fj<2;fj++){
        int col = c*128 + w*32 + fj*16 + lc;
        bf16x8 b = *(const bf16x8*)(m1T + (size_t)col*256 + k0 + lg*8);
#pragma unroll
        for(int fi=0;fi<4;fi++)
          h1[fi][fj] = mfma16(a[fi], b, h1[fi][fj]);
      }
    }
    __syncthreads();
#pragma unroll
    for(int fj=0;fj<2;fj++){
      int col  = c*128 + w*32 + fj*16 + lc;
      int lcol = w*32 + fj*16 + lc;
      float bias = b1[col];
#pragma unroll
      for(int fi=0;fi<4;fi++)
#pragma unroll
        for(int r=0;r<4;r++){
          int row = fi*16 + lg*4 + r;
          float v = h1[fi][fj][r] + bias;
          v = v > 0.f ? v : 0.f;
          *(unsigned short*)((char*)sHD + swzb(row, lcol*2, 256)) = f2bf(v);
        }
    }
    __syncthreads();
    for(int k0=0;k0<128;k0+=32){
      bf16x8 a[4], b[4];
#pragma unroll
      for(int fi=0;fi<4;fi++)
        a[fi] = *(const bf16x8*)((const char*)sHD + swzb(fi*16+lc, (k0+lg*8)*2, 256));
#pragma unroll
      for(int fj=0;fj<4;fj++){
        int col = w*64 + fj*16 + lc;
        b[fj] = *(const bf16x8*)(m2T + (size_t)col*512 + c*128 + k0 + lg*8);
      }
#pragma unroll
      for(int fi=0;fi<4;fi++)
#pragma unroll
        for(int fj=0;fj<4;fj++)
          zacc[fi][fj] = mfma16(a[fi], b[fj], zacc[fi][fj]);
    }
  }

#pragma unroll
  for(int fj=0;fj<4;fj++){
    int col = w*64 + fj*16 + lc;
    float bias = b2[col];
    float s1 = 0.f, s2 = 0.f;
#pragma unroll
    for(int fi=0;fi<4;fi++)
#pragma unroll
      for(int r=0;r<4;r++){
        int gr = m0 + fi*16 + lg*4 + r;
        float v = zacc[fi][fj][r] + bias;
        if(gr < N){
          z[(size_t)gr*HID + col] = v;
          s1 += v; s2 += v*v;
        }
      }
    s1 += __shfl_xor(s1, 16, 64); s1 += __shfl_xor(s1, 32, 64);
    s2 += __shfl_xor(s2, 16, 64); s2 += __shfl_xor(s2, 32, 64);
    if(lg == 0){
      atomicAdd(&stats[col],       s1);
      atomicAdd(&stats[HID + col], s2);
    }
  }
}

__global__ void stats_fin(const float* __restrict__ stats, float* __restrict__ musig, float invN){
  int c = threadIdx.x;
  float mu  = stats[c] * invN;
  float var = stats[HID + c] * invN - mu*mu;
  musig[c]       = mu;
  musig[HID + c] = rsqrtf(var + BN_EPS);
}

__global__ void final_bn(float* __restrict__ out, const float* __restrict__ musig,
                         const float* __restrict__ gamma, const float* __restrict__ beta,
                         long total4){
  for(long i = (long)blockIdx.x*blockDim.x + threadIdx.x; i < total4; i += (long)gridDim.x*blockDim.x){
    int c0 = ((int)(i & 63)) << 2;
    float4 v = ((const float4*)out)[i];
    float o[4] = {v.x, v.y, v.z, v.w};
#pragma unroll
    for(int c=0;c<4;c++)
      o[c] = gamma[c0+c]*(o[c] - musig[c0+c])*musig[256+c0+c] + beta[c0+c];
    float4 ov = {o[0], o[1], o[2], o[3]};
    ((float4*)out)[i] = ov;
  }
}

// ---------------- host ----------------

extern "C" void kernel_launch(void* const* d_in, const int* in_sizes, int n_in,
                              void* d_out, int out_size, void* d_ws, size_t ws_size,
                              hipStream_t stream)
{
  const float* f_atoms = (const float*)d_in[0];
  const float* f_bonds = (const float*)d_in[1];
  const int*   a2b     = (const int*)d_in[2];
  const int*   b2a     = (const int*)d_in[3];
  const float* w_atom  = (const float*)d_in[6];
  const float* wb_w1   = (const float*)d_in[7];
  const float* wb_b1   = (const float*)d_in[8];
  const float* wb_w2   = (const float*)d_in[9];
  const float* wb_b2   = (const float*)d_in[10];
  const float* mlp_w1  = (const float*)d_in[11];
  const float* mlp_b1  = (const float*)d_in[12];
  const float* mlp_w2  = (const float*)d_in[13];
  const float* mlp_b2  = (const float*)d_in[14];
  const float* bn_g    = (const float*)d_in[15];
  const float* bn_b    = (const float*)d_in[16];
  const int N = in_sizes[0] / AFD;
  const int E = in_sizes[3];
  float* out = (float*)d_out;
  (void)n_in; (void)out_size; (void)ws_size;

  char* ws = (char*)d_ws;
  size_t off = 0;
  auto alloc = [&](size_t bytes)->char* {
    char* p = ws + off; off += (bytes + 255) & ~(size_t)255; return p;
  };
  float* hbuf          = (float*)alloc((size_t)N*HID*4);
  unsigned short* msg  = (unsigned short*)alloc((size_t)E*HID*2);
  unsigned short* eb   = (unsigned short*)alloc((size_t)E*16*2);
  unsigned char* cov   = (unsigned char*)alloc((size_t)E);
  unsigned short* wAT  = (unsigned short*)alloc((size_t)HID*KA_PAD*2);
  unsigned short* w1T  = (unsigned short*)alloc((size_t)3*HID*KB_PAD*2);
  unsigned short* w2T  = (unsigned short*)alloc((size_t)3*HID*HID*2);
  unsigned short* m1T  = (unsigned short*)alloc((size_t)3*512*HID*2);
  unsigned short* m2T  = (unsigned short*)alloc((size_t)3*HID*512*2);
  float* sl            = (float*)alloc((size_t)3*HID*4);
  float* stats         = (float*)alloc((size_t)3*512*4);
  float* musig         = (float*)alloc((size_t)3*512*4);
  float* lo            = (float*)alloc((size_t)3*HID*4);

  hipMemsetAsync(stats, 0, (size_t)3*512*4, stream);
  hipMemsetAsync(lo,    0, (size_t)3*HID*4, stream);
  hipMemsetAsync(cov,   0, (size_t)E, stream);

  auto cdiv = [](long a, long b){ return (int)((a + b - 1)/b); };

  pack_wT<<<cdiv((long)HID*KA_PAD,256),256,0,stream>>>(w_atom, wAT, AFD, HID, KA_PAD);
  for(int l=0;l<3;l++){
    pack_wT<<<cdiv((long)HID*KB_PAD,256),256,0,stream>>>(wb_w1 + (size_t)l*16*HID,  w1T + (size_t)l*HID*KB_PAD, 16,  HID, KB_PAD);
    pack_wT<<<cdiv((long)HID*HID,256),256,0,stream>>>(wb_w2 + (size_t)l*HID*HID,  w2T + (size_t)l*HID*HID,  HID, HID, HID);
    pack_wT<<<cdiv((long)512*HID,256),256,0,stream>>>(mlp_w1 + (size_t)l*HID*512, m1T + (size_t)l*512*HID,  HID, 512, HID);
    pack_wT<<<cdiv((long)HID*512,256),256,0,stream>>>(mlp_w2 + (size_t)l*512*HID, m2T + (size_t)l*HID*512,  512, HID, 512);
  }
  pack_eb<<<2048,256,0,stream>>>(f_bonds, eb, E);
  build_cov<<<2048,256,0,stream>>>(a2b, cov, N);
  sl_emb_kernel<<<3,256,0,stream>>>(wb_w1, wb_b1, wb_w2, wb_b2, sl);

  atom_embed<<<cdiv(N,64),256,0,stream>>>(f_atoms, wAT, hbuf, N);

  float* hraw = hbuf;
  float* zdst = out;
  for(int l=0;l<3;l++){
    int applyBN = (l > 0);
    const float* ms = applyBN ? (musig + (size_t)(l-1)*512) : musig;
    const float* gp = applyBN ? (bn_g + (size_t)(l-1)*HID)  : bn_g;
    const float* bp = applyBN ? (bn_b + (size_t)(l-1)*HID)  : bn_b;
    edge_mlp_msg<<<cdiv(E,64),256,0,stream>>>(eb,
        w1T + (size_t)l*HID*KB_PAD, wb_b1 + (size_t)l*HID,
        w2T + (size_t)l*HID*HID,    wb_b2 + (size_t)l*HID,
        b2a, hraw, ms, gp, bp, applyBN, msg, E);
    leftover0<<<512,256,0,stream>>>(msg, cov, lo + (size_t)l*HID, E);
    node_mlp_fused<<<cdiv(N,64),256,0,stream>>>(msg, a2b, hraw,
        sl + (size_t)l*HID, lo + (size_t)l*HID, ms, gp, bp, applyBN,
        m1T + (size_t)l*512*HID, mlp_b1 + (size_t)l*512,
        m2T + (size_t)l*HID*512, mlp_b2 + (size_t)l*HID,
        zdst, stats + (size_t)l*512, N);
    stats_fin<<<1,256,0,stream>>>(stats + (size_t)l*512, musig + (size_t)l*512, 1.0f/(float)N);
    float* tmp = hraw; hraw = zdst; zdst = tmp;
  }
  final_bn<<<2048,256,0,stream>>>(out, musig + 2*512, bn_g + 2*HID, bn_b + 2*HID, (long)N*64);
}

// Round 3
// 2117.613 us; speedup vs baseline: 1.0879x; 1.0879x over previous
//
#include <hip/hip_runtime.h>
#include <hip/hip_bf16.h>

#define HID    256
#define AFD    133
#define KA_PAD 160
#define KB_PAD 32
#define MAXNB  16
#define BN_EPS 1e-5f

typedef __attribute__((ext_vector_type(8))) __bf16 bf16x8;
typedef __attribute__((ext_vector_type(4))) float  f32x4;

__device__ __forceinline__ unsigned short f2bf(float x){
  union { __hip_bfloat16 b; unsigned short u; } cv;
  cv.b = __float2bfloat16(x);
  return cv.u;
}
__device__ __forceinline__ float bf2f(unsigned short u){
  union { unsigned int i; float f; } cv;
  cv.i = ((unsigned int)u) << 16;
  return cv.f;
}

// XOR swizzle on 16B blocks within a row-stripe: kills ds_read_b128 bank conflicts
__device__ __forceinline__ unsigned swzb(int row, int kbyte, int rowStrideB){
  return (unsigned)(row*rowStrideB + kbyte) ^ (unsigned)((row & 7) << 4);
}

__device__ __forceinline__ f32x4 mfma16(bf16x8 a, bf16x8 b, f32x4 c){
  return __builtin_amdgcn_mfma_f32_16x16x32_bf16(a, b, c, 0, 0, 0);
}

// ---------------- packing kernels ----------------

__global__ void pack_wT(const float* __restrict__ W, unsigned short* __restrict__ WT,
                        int K, int Ncols, int Kpad){
  int total = Ncols * Kpad;
  for(int idx = blockIdx.x*blockDim.x + threadIdx.x; idx < total; idx += gridDim.x*blockDim.x){
    int col = idx / Kpad, k = idx - col*Kpad;
    float v = (k < K) ? W[(size_t)k*Ncols + col] : 0.f;
    WT[idx] = f2bf(v);
  }
}

__global__ void pack_eb(const float* __restrict__ fb, unsigned short* __restrict__ eb, int E){
  int total = E*16;
  for(int idx = blockIdx.x*blockDim.x + threadIdx.x; idx < total; idx += gridDim.x*blockDim.x){
    int e = idx >> 4, k = idx & 15;
    float v = (k < 15) ? fb[(size_t)e*15 + k] : 0.f;
    eb[idx] = f2bf(v);
  }
}

__global__ void build_cov(const int* __restrict__ a2b, unsigned char* __restrict__ cov, int N){
  int total = N*MAXNB;
  for(int idx = blockIdx.x*blockDim.x + threadIdx.x; idx < total; idx += gridDim.x*blockDim.x){
    int b = a2b[idx];
    if(b > 0) cov[b] = 1;
  }
}

__global__ void sl_emb_kernel(const float* __restrict__ w1, const float* __restrict__ b1,
                              const float* __restrict__ w2, const float* __restrict__ b2,
                              float* __restrict__ sl){
  int l = blockIdx.x, t = threadIdx.x;
  __shared__ float hid[HID];
  float hv = w1[((size_t)l*16 + 15)*HID + t] + b1[(size_t)l*HID + t];
  hid[t] = hv > 0.f ? hv : 0.f;
  __syncthreads();
  const float* W2 = w2 + (size_t)l*HID*HID;
  float acc = b2[(size_t)l*HID + t];
  for(int k=0;k<HID;k++) acc += hid[k] * W2[(size_t)k*HID + t];
  sl[(size_t)l*HID + t] = acc;
}

// hbn = bf16( BNprev(h) ) ; applyBN=0 -> plain bf16 cast
__global__ void bn_relu_pack(const float* __restrict__ h,
                             const float* __restrict__ musig, const float* __restrict__ gamma,
                             const float* __restrict__ beta, int applyBN,
                             unsigned short* __restrict__ hbn, long total8){
  for(long i = (long)blockIdx.x*blockDim.x + threadIdx.x; i < total8; i += (long)gridDim.x*blockDim.x){
    int c0 = ((int)(i & 31)) << 3;
    float4 v0 = ((const float4*)h)[i*2];
    float4 v1 = ((const float4*)h)[i*2+1];
    float o[8] = {v0.x,v0.y,v0.z,v0.w,v1.x,v1.y,v1.z,v1.w};
    if(applyBN){
#pragma unroll
      for(int c=0;c<8;c++){
        float x = gamma[c0+c]*(o[c] - musig[c0+c])*musig[256+c0+c] + beta[c0+c];
        o[c] = x > 0.f ? x : 0.f;
      }
    }
    union { uint4 v; unsigned short us[8]; } pk;
#pragma unroll
    for(int c=0;c<8;c++) pk.us[c] = f2bf(o[c]);
    ((uint4*)hbn)[i] = pk.v;
  }
}

// ---------------- h0 = f_atoms @ w_atom ----------------

__global__ __launch_bounds__(256,2) void atom_embed(
    const float* __restrict__ fat, const unsigned short* __restrict__ wAT,
    float* __restrict__ h, int N)
{
  __shared__ alignas(16) unsigned short sA[64*KA_PAD];
  const int t = threadIdx.x;
  const int m0 = blockIdx.x*64;
  for(int i=t; i<64*KA_PAD; i+=256){
    int row = i / KA_PAD;
    int k   = i - row*KA_PAD;
    int gr  = m0 + row;
    float v = (gr < N && k < AFD) ? fat[(size_t)gr*AFD + k] : 0.f;
    *(unsigned short*)((char*)sA + swzb(row, k*2, KA_PAD*2)) = f2bf(v);
  }
  __syncthreads();
  const int w = t>>6, l = t&63, lg = l>>4, lc = l&15;
  const f32x4 z4 = {0.f,0.f,0.f,0.f};
  f32x4 acc[4][4];
#pragma unroll
  for(int fi=0;fi<4;fi++)
#pragma unroll
    for(int fj=0;fj<4;fj++) acc[fi][fj] = z4;
  for(int k0=0;k0<KA_PAD;k0+=32){
    bf16x8 a[4], b[4];
#pragma unroll
    for(int fi=0;fi<4;fi++)
      a[fi] = *(const bf16x8*)((const char*)sA + swzb(fi*16+lc, (k0+lg*8)*2, KA_PAD*2));
#pragma unroll
    for(int fj=0;fj<4;fj++){
      int col = w*64 + fj*16 + lc;
      b[fj] = *(const bf16x8*)(wAT + (size_t)col*KA_PAD + k0 + lg*8);
    }
#pragma unroll
    for(int fi=0;fi<4;fi++)
#pragma unroll
      for(int fj=0;fj<4;fj++)
        acc[fi][fj] = mfma16(a[fi], b[fj], acc[fi][fj]);
  }
#pragma unroll
  for(int fj=0;fj<4;fj++){
    int col = w*64 + fj*16 + lc;
#pragma unroll
    for(int fi=0;fi<4;fi++)
#pragma unroll
      for(int r=0;r<4;r++){
        int gr = m0 + fi*16 + lg*4 + r;
        if(gr < N) h[(size_t)gr*HID + col] = acc[fi][fj][r];
      }
  }
}

// ---------------- edge MLP -> msg = e_emb + b2 + hbn[b2a] ----------------

__global__ __launch_bounds__(256,4) void edge_mlp_msg(
    const unsigned short* __restrict__ eb,
    const unsigned short* __restrict__ w1T, const float* __restrict__ b1,
    const unsigned short* __restrict__ w2T, const float* __restrict__ b2,
    const int* __restrict__ b2a,
    const unsigned short* __restrict__ hbn,
    unsigned short* __restrict__ msg, int E)
{
  __shared__ alignas(16) unsigned short sEB[64*32];
  __shared__ alignas(16) unsigned short sH[64*256];
  __shared__ int sB2A[64];
  const int t  = threadIdx.x;
  const int e0 = blockIdx.x*64;
  {
    int row = t >> 2;
    int kc  = (t & 3) << 3;
    uint4 val = make_uint4(0,0,0,0);
    int e = e0 + row;
    if(kc < 16 && e < E) val = *(const uint4*)(eb + (size_t)e*16 + kc);
    *(uint4*)((char*)sEB + swzb(row, kc*2, 64)) = val;
  }
  if(t < 64){
    int e = e0 + t;
    sB2A[t] = (e < E) ? b2a[e] : 0;
  }
  __syncthreads();

  const int w = t>>6, l = t&63, lg = l>>4, lc = l&15;
  const f32x4 z4 = {0.f,0.f,0.f,0.f};

  { // stage 1: hid1 = relu(eb @ w1 + b1) -> sH (bf16)
    bf16x8 a[4], b[4];
#pragma unroll
    for(int fi=0;fi<4;fi++)
      a[fi] = *(const bf16x8*)((const char*)sEB + swzb(fi*16+lc, lg*16, 64));
#pragma unroll
    for(int fj=0;fj<4;fj++){
      int col = w*64 + fj*16 + lc;
      b[fj] = *(const bf16x8*)(w1T + (size_t)col*KB_PAD + lg*8);
    }
    f32x4 s1[4][4];
#pragma unroll
    for(int fi=0;fi<4;fi++)
#pragma unroll
      for(int fj=0;fj<4;fj++)
        s1[fi][fj] = mfma16(a[fi], b[fj], z4);
#pragma unroll
    for(int fj=0;fj<4;fj++){
      int col = w*64 + fj*16 + lc;
      float bias = b1[col];
#pragma unroll
      for(int fi=0;fi<4;fi++)
#pragma unroll
        for(int r=0;r<4;r++){
          int row = fi*16 + lg*4 + r;
          float v = s1[fi][fj][r] + bias;
          v = v > 0.f ? v : 0.f;
          *(unsigned short*)((char*)sH + swzb(row, col*2, 512)) = f2bf(v);
        }
    }
  }
  __syncthreads();

  // stage 2: e_emb = hid1 @ w2
  f32x4 acc[4][4];
#pragma unroll
  for(int fi=0;fi<4;fi++)
#pragma unroll
    for(int fj=0;fj<4;fj++) acc[fi][fj] = z4;
  for(int k0=0;k0<256;k0+=32){
    bf16x8 a[4], b[4];
#pragma unroll
    for(int fi=0;fi<4;fi++)
      a[fi] = *(const bf16x8*)((const char*)sH + swzb(fi*16+lc, (k0+lg*8)*2, 512));
#pragma unroll
    for(int fj=0;fj<4;fj++){
      int col = w*64 + fj*16 + lc;
      b[fj] = *(const bf16x8*)(w2T + (size_t)col*256 + k0 + lg*8);
    }
#pragma unroll
    for(int fi=0;fi<4;fi++)
#pragma unroll
      for(int fj=0;fj<4;fj++)
        acc[fi][fj] = mfma16(a[fi], b[fj], acc[fi][fj]);
  }
  __syncthreads();   // all waves done reading sH; about to overwrite

  // epilogue A: sH = bf16(e_emb + b2)
#pragma unroll
  for(int fj=0;fj<4;fj++){
    int col = w*64 + fj*16 + lc;
    float bias = b2[col];
#pragma unroll
    for(int fi=0;fi<4;fi++)
#pragma unroll
      for(int r=0;r<4;r++){
        int row = fi*16 + lg*4 + r;
        *(unsigned short*)((char*)sH + swzb(row, col*2, 512)) = f2bf(acc[fi][fj][r] + bias);
      }
  }
  __syncthreads();

  // epilogue B: msg[e] = sH[row] + hbn[b2a[row]]  (vectorized, coalesced)
  for(int c=t; c<2048; c+=256){
    int row = c >> 5;
    int q   = c & 31;
    int e   = e0 + row;
    if(e < E){
      union { uint4 v; unsigned short us[8]; } ua, ub, uo;
      ua.v = *(const uint4*)((const char*)sH + swzb(row, q*16, 512));
      ub.v = ((const uint4*)(hbn + (size_t)sB2A[row]*HID))[q];
#pragma unroll
      for(int x=0;x<8;x++) uo.us[x] = f2bf(bf2f(ua.us[x]) + bf2f(ub.us[x]));
      ((uint4*)(msg + (size_t)e*HID))[q] = uo.v;
    }
  }
}

// sum msg over uncovered bonds into leftover[256] (these route to atom 0)
__global__ void leftover0(const unsigned short* __restrict__ msg,
                          const unsigned char* __restrict__ cov,
                          float* __restrict__ lo, int E)
{
  int gw   = (blockIdx.x*blockDim.x + threadIdx.x) >> 6;
  int lane = threadIdx.x & 63;
  int nw   = (gridDim.x*blockDim.x) >> 6;
  for(int e = gw; e < E; e += nw){
    if(!cov[e]){
#pragma unroll
      for(int q=0;q<4;q++){
        int col = q*64 + lane;
        atomicAdd(&lo[col], bf2f(msg[(size_t)e*256 + col]));
      }
    }
  }
}

// ---------------- fused gather + node MLP + BN stats ----------------

__global__ __launch_bounds__(256,3) void node_mlp_fused(
    const unsigned short* __restrict__ msg,
    const int* __restrict__ a2b,
    const unsigned short* __restrict__ hbn, const float* __restrict__ sl,
    const float* __restrict__ lo,
    const unsigned short* __restrict__ m1T, const float* __restrict__ b1,
    const unsigned short* __restrict__ m2T, const float* __restrict__ b2,
    float* __restrict__ z, float* __restrict__ stats, int N)
{
  __shared__ alignas(16) unsigned short sA [64*256];
  __shared__ alignas(16) unsigned short sHD[64*128];
  const int t  = threadIdx.x;
  const int m0 = blockIdx.x*64;

  // staging: aggr_row = hbn[gr] + sl + sum_j msg[a2b[gr][j]] (+ leftover at atom 0)
  for(int p=0;p<2;p++){
    int row = p*32 + (t>>3);
    int gr  = m0 + row;
    int c0  = (t&7)*32;
    float acc[32];
    if(gr < N){
      const unsigned short* hp = hbn + (size_t)gr*HID + c0;
#pragma unroll
      for(int q=0;q<4;q++){
        union { uint4 v; unsigned short us[8]; } hv;
        hv.v = *(const uint4*)(hp + q*8);
#pragma unroll
        for(int x=0;x<8;x++) acc[q*8+x] = bf2f(hv.us[x]);
      }
#pragma unroll
      for(int k=0;k<32;k++) acc[k] += sl[c0+k];
      if(gr == 0){
#pragma unroll
        for(int k=0;k<32;k++) acc[k] += lo[c0+k];
      }
      const int* ab = a2b + (size_t)gr*MAXNB;
      int bidx[MAXNB];
#pragma unroll
      for(int j4=0;j4<4;j4++){
        int4 iv = *(const int4*)(ab + j4*4);
        bidx[j4*4+0]=iv.x; bidx[j4*4+1]=iv.y; bidx[j4*4+2]=iv.z; bidx[j4*4+3]=iv.w;
      }
#pragma unroll
      for(int j=0;j<MAXNB;j++){
        int b = bidx[j];
        if(b > 0){
          const unsigned short* mp = msg + (size_t)b*HID + c0;
#pragma unroll
          for(int q=0;q<4;q++){
            union { uint4 v; unsigned short us[8]; } mv;
            mv.v = *(const uint4*)(mp + q*8);
#pragma unroll
            for(int x=0;x<8;x++) acc[q*8+x] += bf2f(mv.us[x]);
          }
        }
      }
    } else {
#pragma unroll
      for(int k=0;k<32;k++) acc[k] = 0.f;
    }
#pragma unroll
    for(int q=0;q<4;q++){
      union { uint4 v; unsigned short us[8]; } pk;
#pragma unroll
      for(int x=0;x<8;x++) pk.us[x] = f2bf(acc[q*8+x]);
      *(uint4*)((char*)sA + swzb(row, (c0+q*8)*2, 512)) = pk.v;
    }
  }
  __syncthreads();

  const int w = t>>6, l = t&63, lg = l>>4, lc = l&15;
  const f32x4 z4 = {0.f,0.f,0.f,0.f};
  f32x4 zacc[4][4];
#pragma unroll
  for(int fi=0;fi<4;fi++)
#pragma unroll
    for(int fj=0;fj<4;fj++) zacc[fi][fj] = z4;

  for(int c=0;c<4;c++){
    f32x4 h1[4][2];
#pragma unroll
    for(int fi=0;fi<4;fi++){ h1[fi][0] = z4; h1[fi][1] = z4; }
    for(int k0=0;k0<256;k0+=32){
      bf16x8 a[4];
#pragma unroll
      for(int fi=0;fi<4;fi++)
        a[fi] = *(const bf16x8*)((const char*)sA + swzb(fi*16+lc, (k0+lg*8)*2, 512));
#pragma unroll
      for(int fj=0;fj<2;fj++){
        int col = c*128 + w*32 + fj*16 + lc;
        bf16x8 b = *(const bf16x8*)(m1T + (size_t)col*256 + k0 + lg*8);
#pragma unroll
        for(int fi=0;fi<4;fi++)
          h1[fi][fj] = mfma16(a[fi], b, h1[fi][fj]);
      }
    }
    __syncthreads();
#pragma unroll
    for(int fj=0;fj<2;fj++){
      int col  = c*128 + w*32 + fj*16 + lc;
      int lcol = w*32 + fj*16 + lc;
      float bias = b1[col];
#pragma unroll
      for(int fi=0;fi<4;fi++)
#pragma unroll
        for(int r=0;r<4;r++){
          int row = fi*16 + lg*4 + r;
          float v = h1[fi][fj][r] + bias;
          v = v > 0.f ? v : 0.f;
          *(unsigned short*)((char*)sHD + swzb(row, lcol*2, 256)) = f2bf(v);
        }
    }
    __syncthreads();
    for(int k0=0;k0<128;k0+=32){
      bf16x8 a[4], b[4];
#pragma unroll
      for(int fi=0;fi<4;fi++)
        a[fi] = *(const bf16x8*)((const char*)sHD + swzb(fi*16+lc, (k0+lg*8)*2, 256));
#pragma unroll
      for(int fj=0;fj<4;fj++){
        int col = w*64 + fj*16 + lc;
        b[fj] = *(const bf16x8*)(m2T + (size_t)col*512 + c*128 + k0 + lg*8);
      }
#pragma unroll
      for(int fi=0;fi<4;fi++)
#pragma unroll
        for(int fj=0;fj<4;fj++)
          zacc[fi][fj] = mfma16(a[fi], b[fj], zacc[fi][fj]);
    }
  }

#pragma unroll
  for(int fj=0;fj<4;fj++){
    int col = w*64 + fj*16 + lc;
    float bias = b2[col];
    float s1 = 0.f, s2 = 0.f;
#pragma unroll
    for(int fi=0;fi<4;fi++)
#pragma unroll
      for(int r=0;r<4;r++){
        int gr = m0 + fi*16 + lg*4 + r;
        float v = zacc[fi][fj][r] + bias;
        if(gr < N){
          z[(size_t)gr*HID + col] = v;
          s1 += v; s2 += v*v;
        }
      }
    s1 += __shfl_xor(s1, 16, 64); s1 += __shfl_xor(s1, 32, 64);
    s2 += __shfl_xor(s2, 16, 64); s2 += __shfl_xor(s2, 32, 64);
    if(lg == 0){
      atomicAdd(&stats[col],       s1);
      atomicAdd(&stats[HID + col], s2);
    }
  }
}

__global__ void stats_fin(const float* __restrict__ stats, float* __restrict__ musig, float invN){
  int c = threadIdx.x;
  float mu  = stats[c] * invN;
  float var = stats[HID + c] * invN - mu*mu;
  musig[c]       = mu;
  musig[HID + c] = rsqrtf(var + BN_EPS);
}

__global__ void final_bn(float* __restrict__ out, const float* __restrict__ musig,
                         const float* __restrict__ gamma, const float* __restrict__ beta,
                         long total4){
  for(long i = (long)blockIdx.x*blockDim.x + threadIdx.x; i < total4; i += (long)gridDim.x*blockDim.x){
    int c0 = ((int)(i & 63)) << 2;
    float4 v = ((const float4*)out)[i];
    float o[4] = {v.x, v.y, v.z, v.w};
#pragma unroll
    for(int c=0;c<4;c++)
      o[c] = gamma[c0+c]*(o[c] - musig[c0+c])*musig[256+c0+c] + beta[c0+c];
    float4 ov = {o[0], o[1], o[2], o[3]};
    ((float4*)out)[i] = ov;
  }
}

// ---------------- host ----------------

extern "C" void kernel_launch(void* const* d_in, const int* in_sizes, int n_in,
                              void* d_out, int out_size, void* d_ws, size_t ws_size,
                              hipStream_t stream)
{
  const float* f_atoms = (const float*)d_in[0];
  const float* f_bonds = (const float*)d_in[1];
  const int*   a2b     = (const int*)d_in[2];
  const int*   b2a     = (const int*)d_in[3];
  const float* w_atom  = (const float*)d_in[6];
  const float* wb_w1   = (const float*)d_in[7];
  const float* wb_b1   = (const float*)d_in[8];
  const float* wb_w2   = (const float*)d_in[9];
  const float* wb_b2   = (const float*)d_in[10];
  const float* mlp_w1  = (const float*)d_in[11];
  const float* mlp_b1  = (const float*)d_in[12];
  const float* mlp_w2  = (const float*)d_in[13];
  const float* mlp_b2  = (const float*)d_in[14];
  const float* bn_g    = (const float*)d_in[15];
  const float* bn_b    = (const float*)d_in[16];
  const int N = in_sizes[0] / AFD;
  const int E = in_sizes[3];
  float* out = (float*)d_out;
  (void)n_in; (void)out_size; (void)ws_size;

  char* ws = (char*)d_ws;
  size_t off = 0;
  auto alloc = [&](size_t bytes)->char* {
    char* p = ws + off; off += (bytes + 255) & ~(size_t)255; return p;
  };
  float* hbuf          = (float*)alloc((size_t)N*HID*4);
  unsigned short* hbn  = (unsigned short*)alloc((size_t)N*HID*2);
  unsigned short* msg  = (unsigned short*)alloc((size_t)E*HID*2);
  unsigned short* eb   = (unsigned short*)alloc((size_t)E*16*2);
  unsigned char* cov   = (unsigned char*)alloc((size_t)E);
  unsigned short* wAT  = (unsigned short*)alloc((size_t)HID*KA_PAD*2);
  unsigned short* w1T  = (unsigned short*)alloc((size_t)3*HID*KB_PAD*2);
  unsigned short* w2T  = (unsigned short*)alloc((size_t)3*HID*HID*2);
  unsigned short* m1T  = (unsigned short*)alloc((size_t)3*512*HID*2);
  unsigned short* m2T  = (unsigned short*)alloc((size_t)3*HID*512*2);
  float* sl            = (float*)alloc((size_t)3*HID*4);
  float* stats         = (float*)alloc((size_t)3*512*4);
  float* musig         = (float*)alloc((size_t)3*512*4);
  float* lo            = (float*)alloc((size_t)3*HID*4);

  hipMemsetAsync(stats, 0, (size_t)3*512*4, stream);
  hipMemsetAsync(lo,    0, (size_t)3*HID*4, stream);
  hipMemsetAsync(cov,   0, (size_t)E, stream);

  auto cdiv = [](long a, long b){ return (int)((a + b - 1)/b); };

  pack_wT<<<cdiv((long)HID*KA_PAD,256),256,0,stream>>>(w_atom, wAT, AFD, HID, KA_PAD);
  for(int l=0;l<3;l++){
    pack_wT<<<cdiv((long)HID*KB_PAD,256),256,0,stream>>>(wb_w1 + (size_t)l*16*HID,  w1T + (size_t)l*HID*KB_PAD, 16,  HID, KB_PAD);
    pack_wT<<<cdiv((long)HID*HID,256),256,0,stream>>>(wb_w2 + (size_t)l*HID*HID,  w2T + (size_t)l*HID*HID,  HID, HID, HID);
    pack_wT<<<cdiv((long)512*HID,256),256,0,stream>>>(mlp_w1 + (size_t)l*HID*512, m1T + (size_t)l*512*HID,  HID, 512, HID);
    pack_wT<<<cdiv((long)HID*512,256),256,0,stream>>>(mlp_w2 + (size_t)l*512*HID, m2T + (size_t)l*HID*512,  512, HID, 512);
  }
  pack_eb<<<2048,256,0,stream>>>(f_bonds, eb, E);
  build_cov<<<2048,256,0,stream>>>(a2b, cov, N);
  sl_emb_kernel<<<3,256,0,stream>>>(wb_w1, wb_b1, wb_w2, wb_b2, sl);

  atom_embed<<<cdiv(N,64),256,0,stream>>>(f_atoms, wAT, hbuf, N);

  float* hraw = hbuf;
  float* zdst = out;
  for(int l=0;l<3;l++){
    int applyBN = (l > 0);
    const float* ms = applyBN ? (musig + (size_t)(l-1)*512) : musig;
    const float* gp = applyBN ? (bn_g + (size_t)(l-1)*HID)  : bn_g;
    const float* bp = applyBN ? (bn_b + (size_t)(l-1)*HID)  : bn_b;
    bn_relu_pack<<<2048,256,0,stream>>>(hraw, ms, gp, bp, applyBN, hbn, (long)N*32);
    edge_mlp_msg<<<cdiv(E,64),256,0,stream>>>(eb,
        w1T + (size_t)l*HID*KB_PAD, wb_b1 + (size_t)l*HID,
        w2T + (size_t)l*HID*HID,    wb_b2 + (size_t)l*HID,
        b2a, hbn, msg, E);
    leftover0<<<512,256,0,stream>>>(msg, cov, lo + (size_t)l*HID, E);
    node_mlp_fused<<<cdiv(N,64),256,0,stream>>>(msg, a2b, hbn,
        sl + (size_t)l*HID, lo + (size_t)l*HID,
        m1T + (size_t)l*512*HID, mlp_b1 + (size_t)l*512,
        m2T + (size_t)l*HID*512, mlp_b2 + (size_t)l*HID,
        zdst, stats + (size_t)l*512, N);
    stats_fin<<<1,256,0,stream>>>(stats + (size_t)l*512, musig + (size_t)l*512, 1.0f/(float)N);
    float* tmp = hraw; hraw = zdst; zdst = tmp;
  }
  final_bn<<<2048,256,0,stream>>>(out, musig + 2*512, bn_g + 2*HID, bn_b + 2*HID, (long)N*64);
}

// Round 4
// 1887.473 us; speedup vs baseline: 1.2206x; 1.1219x over previous
//
#include <hip/hip_runtime.h>
#include <hip/hip_bf16.h>

#define HID    256
#define AFD    133
#define KA_PAD 160
#define KB_PAD 32
#define MAXNB  16
#define BN_EPS 1e-5f

typedef __attribute__((ext_vector_type(8))) __bf16 bf16x8;
typedef __attribute__((ext_vector_type(4))) float  f32x4;

__device__ __forceinline__ unsigned short f2bf(float x){
  union { __hip_bfloat16 b; unsigned short u; } cv;
  cv.b = __float2bfloat16(x);
  return cv.u;
}
__device__ __forceinline__ float bf2f(unsigned short u){
  union { unsigned int i; float f; } cv;
  cv.i = ((unsigned int)u) << 16;
  return cv.f;
}

// XOR swizzle on 16B blocks within a row-stripe: kills ds_read_b128 bank conflicts
__device__ __forceinline__ unsigned swzb(int row, int kbyte, int rowStrideB){
  return (unsigned)(row*rowStrideB + kbyte) ^ (unsigned)((row & 7) << 4);
}

__device__ __forceinline__ f32x4 mfma16(bf16x8 a, bf16x8 b, f32x4 c){
  return __builtin_amdgcn_mfma_f32_16x16x32_bf16(a, b, c, 0, 0, 0);
}

// ---------------- packing kernels ----------------

__global__ void pack_wT(const float* __restrict__ W, unsigned short* __restrict__ WT,
                        int K, int Ncols, int Kpad){
  int total = Ncols * Kpad;
  for(int idx = blockIdx.x*blockDim.x + threadIdx.x; idx < total; idx += gridDim.x*blockDim.x){
    int col = idx / Kpad, k = idx - col*Kpad;
    float v = (k < K) ? W[(size_t)k*Ncols + col] : 0.f;
    WT[idx] = f2bf(v);
  }
}

__global__ void pack_eb(const float* __restrict__ fb, unsigned short* __restrict__ eb, int E){
  int total = E*16;
  for(int idx = blockIdx.x*blockDim.x + threadIdx.x; idx < total; idx += gridDim.x*blockDim.x){
    int e = idx >> 4, k = idx & 15;
    float v = (k < 15) ? fb[(size_t)e*15 + k] : 0.f;
    eb[idx] = f2bf(v);
  }
}

// ---------------- CSR slot machinery ----------------

// per-atom in-degree + intra-block exclusive scan; partials[block] = block sum
__global__ void count_scan(const int* __restrict__ a2b, int* __restrict__ offs_local,
                           int* __restrict__ partials, int N){
  __shared__ int s[256];
  int t = threadIdx.x;
  int a = blockIdx.x*256 + t;
  int c = 0;
  if(a < N){
    const int* ab = a2b + (size_t)a*MAXNB;
#pragma unroll
    for(int j4=0;j4<4;j4++){
      int4 iv = *(const int4*)(ab + j4*4);
      c += (iv.x>0) + (iv.y>0) + (iv.z>0) + (iv.w>0);
    }
  }
  s[t] = c;
  __syncthreads();
  for(int off=1; off<256; off<<=1){
    int u = (t>=off) ? s[t-off] : 0;
    __syncthreads();
    s[t] += u;
    __syncthreads();
  }
  if(a < N) offs_local[a] = s[t] - c;   // exclusive within block
  if(t == 255) partials[blockIdx.x] = s[255];
}

// single-block exclusive scan of partials (nb <= 512)
__global__ void scan_partials(int* __restrict__ partials, int nb, int* __restrict__ total){
  __shared__ int s[512];
  int t = threadIdx.x;
  int v = (t < nb) ? partials[t] : 0;
  s[t] = v;
  __syncthreads();
  for(int off=1; off<512; off<<=1){
    int u = (t>=off) ? s[t-off] : 0;
    __syncthreads();
    s[t] += u;
    __syncthreads();
  }
  if(t < nb) partials[t] = s[t] - v;    // exclusive base per block
  if(t == 511) *total = s[511];
}

__global__ void add_base(const int* __restrict__ offs_local, const int* __restrict__ partials,
                         const int* __restrict__ total, int* __restrict__ offsets, int N){
  for(int i = blockIdx.x*blockDim.x + threadIdx.x; i < N; i += gridDim.x*blockDim.x)
    offsets[i] = offs_local[i] + partials[i >> 8];
  if(blockIdx.x == 0 && threadIdx.x == 0) offsets[N] = *total;
}

// b2slot[b] = offsets[a] + j  for a2b[a][j] = b > 0  (b2slot pre-set to -1)
__global__ void build_slot(const int* __restrict__ a2b, const int* __restrict__ offsets,
                           int* __restrict__ b2slot, int N){
  int totalIdx = N*MAXNB;
  for(int idx = blockIdx.x*blockDim.x + threadIdx.x; idx < totalIdx; idx += gridDim.x*blockDim.x){
    int b = a2b[idx];
    if(b > 0) b2slot[b] = offsets[idx >> 4] + (idx & 15);
  }
}

// ---------------- misc small kernels ----------------

__global__ void sl_emb_kernel(const float* __restrict__ w1, const float* __restrict__ b1,
                              const float* __restrict__ w2, const float* __restrict__ b2,
                              float* __restrict__ sl){
  int l = blockIdx.x, t = threadIdx.x;
  __shared__ float hid[HID];
  float hv = w1[((size_t)l*16 + 15)*HID + t] + b1[(size_t)l*HID + t];
  hid[t] = hv > 0.f ? hv : 0.f;
  __syncthreads();
  const float* W2 = w2 + (size_t)l*HID*HID;
  float acc = b2[(size_t)l*HID + t];
  for(int k=0;k<HID;k++) acc += hid[k] * W2[(size_t)k*HID + t];
  sl[(size_t)l*HID + t] = acc;
}

// hbn = bf16( BNprev(h) ) ; applyBN=0 -> plain bf16 cast
__global__ void bn_relu_pack(const float* __restrict__ h,
                             const float* __restrict__ musig, const float* __restrict__ gamma,
                             const float* __restrict__ beta, int applyBN,
                             unsigned short* __restrict__ hbn, long total8){
  for(long i = (long)blockIdx.x*blockDim.x + threadIdx.x; i < total8; i += (long)gridDim.x*blockDim.x){
    int c0 = ((int)(i & 31)) << 3;
    float4 v0 = ((const float4*)h)[i*2];
    float4 v1 = ((const float4*)h)[i*2+1];
    float o[8] = {v0.x,v0.y,v0.z,v0.w,v1.x,v1.y,v1.z,v1.w};
    if(applyBN){
#pragma unroll
      for(int c=0;c<8;c++){
        float x = gamma[c0+c]*(o[c] - musig[c0+c])*musig[256+c0+c] + beta[c0+c];
        o[c] = x > 0.f ? x : 0.f;
      }
    }
    union { uint4 v; unsigned short us[8]; } pk;
#pragma unroll
    for(int c=0;c<8;c++) pk.us[c] = f2bf(o[c]);
    ((uint4*)hbn)[i] = pk.v;
  }
}

// ---------------- h0 = f_atoms @ w_atom ----------------

__global__ __launch_bounds__(256,2) void atom_embed(
    const float* __restrict__ fat, const unsigned short* __restrict__ wAT,
    float* __restrict__ h, int N)
{
  __shared__ alignas(16) unsigned short sA[64*KA_PAD];
  const int t = threadIdx.x;
  const int m0 = blockIdx.x*64;
  for(int i=t; i<64*KA_PAD; i+=256){
    int row = i / KA_PAD;
    int k   = i - row*KA_PAD;
    int gr  = m0 + row;
    float v = (gr < N && k < AFD) ? fat[(size_t)gr*AFD + k] : 0.f;
    *(unsigned short*)((char*)sA + swzb(row, k*2, KA_PAD*2)) = f2bf(v);
  }
  __syncthreads();
  const int w = t>>6, l = t&63, lg = l>>4, lc = l&15;
  const f32x4 z4 = {0.f,0.f,0.f,0.f};
  f32x4 acc[4][4];
#pragma unroll
  for(int fi=0;fi<4;fi++)
#pragma unroll
    for(int fj=0;fj<4;fj++) acc[fi][fj] = z4;
  for(int k0=0;k0<KA_PAD;k0+=32){
    bf16x8 a[4], b[4];
#pragma unroll
    for(int fi=0;fi<4;fi++)
      a[fi] = *(const bf16x8*)((const char*)sA + swzb(fi*16+lc, (k0+lg*8)*2, KA_PAD*2));
#pragma unroll
    for(int fj=0;fj<4;fj++){
      int col = w*64 + fj*16 + lc;
      b[fj] = *(const bf16x8*)(wAT + (size_t)col*KA_PAD + k0 + lg*8);
    }
#pragma unroll
    for(int fi=0;fi<4;fi++)
#pragma unroll
      for(int fj=0;fj<4;fj++)
        acc[fi][fj] = mfma16(a[fi], b[fj], acc[fi][fj]);
  }
#pragma unroll
  for(int fj=0;fj<4;fj++){
    int col = w*64 + fj*16 + lc;
#pragma unroll
    for(int fi=0;fi<4;fi++)
#pragma unroll
      for(int r=0;r<4;r++){
        int gr = m0 + fi*16 + lg*4 + r;
        if(gr < N) h[(size_t)gr*HID + col] = acc[fi][fj][r];
      }
  }
}

// ---------------- edge MLP -> msg[slot] = e_emb + b2 + hbn[b2a] ----------------

__global__ __launch_bounds__(256,4) void edge_mlp_msg(
    const unsigned short* __restrict__ eb,
    const unsigned short* __restrict__ w1T, const float* __restrict__ b1,
    const unsigned short* __restrict__ w2T, const float* __restrict__ b2,
    const int* __restrict__ b2a, const int* __restrict__ b2slot,
    const unsigned short* __restrict__ hbn,
    unsigned short* __restrict__ msg, float* __restrict__ lo, int E)
{
  __shared__ alignas(16) unsigned short sEB[64*32];
  __shared__ alignas(16) unsigned short sH[64*256];
  __shared__ int sB2A[64], sSLOT[64];
  const int t  = threadIdx.x;
  const int e0 = blockIdx.x*64;
  {
    int row = t >> 2;
    int kc  = (t & 3) << 3;
    uint4 val = make_uint4(0,0,0,0);
    int e = e0 + row;
    if(kc < 16 && e < E) val = *(const uint4*)(eb + (size_t)e*16 + kc);
    *(uint4*)((char*)sEB + swzb(row, kc*2, 64)) = val;
  }
  if(t < 64){
    int e = e0 + t;
    sB2A[t]  = (e < E) ? b2a[e]    : 0;
    sSLOT[t] = (e < E) ? b2slot[e] : -1;
  }
  __syncthreads();

  const int w = t>>6, l = t&63, lg = l>>4, lc = l&15;
  const f32x4 z4 = {0.f,0.f,0.f,0.f};

  { // stage 1: hid1 = relu(eb @ w1 + b1) -> sH (bf16)
    bf16x8 a[4], b[4];
#pragma unroll
    for(int fi=0;fi<4;fi++)
      a[fi] = *(const bf16x8*)((const char*)sEB + swzb(fi*16+lc, lg*16, 64));
#pragma unroll
    for(int fj=0;fj<4;fj++){
      int col = w*64 + fj*16 + lc;
      b[fj] = *(const bf16x8*)(w1T + (size_t)col*KB_PAD + lg*8);
    }
    f32x4 s1[4][4];
#pragma unroll
    for(int fi=0;fi<4;fi++)
#pragma unroll
      for(int fj=0;fj<4;fj++)
        s1[fi][fj] = mfma16(a[fi], b[fj], z4);
#pragma unroll
    for(int fj=0;fj<4;fj++){
      int col = w*64 + fj*16 + lc;
      float bias = b1[col];
#pragma unroll
      for(int fi=0;fi<4;fi++)
#pragma unroll
        for(int r=0;r<4;r++){
          int row = fi*16 + lg*4 + r;
          float v = s1[fi][fj][r] + bias;
          v = v > 0.f ? v : 0.f;
          *(unsigned short*)((char*)sH + swzb(row, col*2, 512)) = f2bf(v);
        }
    }
  }
  __syncthreads();

  // stage 2: e_emb = hid1 @ w2
  f32x4 acc[4][4];
#pragma unroll
  for(int fi=0;fi<4;fi++)
#pragma unroll
    for(int fj=0;fj<4;fj++) acc[fi][fj] = z4;
  for(int k0=0;k0<256;k0+=32){
    bf16x8 a[4], b[4];
#pragma unroll
    for(int fi=0;fi<4;fi++)
      a[fi] = *(const bf16x8*)((const char*)sH + swzb(fi*16+lc, (k0+lg*8)*2, 512));
#pragma unroll
    for(int fj=0;fj<4;fj++){
      int col = w*64 + fj*16 + lc;
      b[fj] = *(const bf16x8*)(w2T + (size_t)col*256 + k0 + lg*8);
    }
#pragma unroll
    for(int fi=0;fi<4;fi++)
#pragma unroll
      for(int fj=0;fj<4;fj++)
        acc[fi][fj] = mfma16(a[fi], b[fj], acc[fi][fj]);
  }
  __syncthreads();   // all waves done reading sH; about to overwrite

  // epilogue A: sH = bf16(e_emb + b2)
#pragma unroll
  for(int fj=0;fj<4;fj++){
    int col = w*64 + fj*16 + lc;
    float bias = b2[col];
#pragma unroll
    for(int fi=0;fi<4;fi++)
#pragma unroll
      for(int r=0;r<4;r++){
        int row = fi*16 + lg*4 + r;
        *(unsigned short*)((char*)sH + swzb(row, col*2, 512)) = f2bf(acc[fi][fj][r] + bias);
      }
  }
  __syncthreads();

  // epilogue B: msg[slot(e)] = sH[row] + hbn[b2a[row]]; uncovered -> atomic into lo
  for(int c=t; c<2048; c+=256){
    int row = c >> 5;
    int q   = c & 31;
    int e   = e0 + row;
    if(e < E){
      union { uint4 v; unsigned short us[8]; } ua, ub, uo;
      ua.v = *(const uint4*)((const char*)sH + swzb(row, q*16, 512));
      ub.v = ((const uint4*)(hbn + (size_t)sB2A[row]*HID))[q];
#pragma unroll
      for(int x=0;x<8;x++) uo.us[x] = f2bf(bf2f(ua.us[x]) + bf2f(ub.us[x]));
      int slot = sSLOT[row];
      if(slot >= 0){
        ((uint4*)(msg + (size_t)slot*HID))[q] = uo.v;
      } else {
#pragma unroll
        for(int x=0;x<8;x++) atomicAdd(&lo[q*8+x], bf2f(uo.us[x]));
      }
    }
  }
}

// ---------------- fused gather + node MLP + BN stats ----------------

__global__ __launch_bounds__(256,3) void node_mlp_fused(
    const unsigned short* __restrict__ msg,
    const int* __restrict__ offsets,
    const unsigned short* __restrict__ hbn, const float* __restrict__ sl,
    const float* __restrict__ lo,
    const unsigned short* __restrict__ m1T, const float* __restrict__ b1,
    const unsigned short* __restrict__ m2T, const float* __restrict__ b2,
    float* __restrict__ z, float* __restrict__ stats, int N)
{
  __shared__ alignas(16) unsigned short sA [64*256];
  __shared__ alignas(16) unsigned short sHD[64*128];
  const int t  = threadIdx.x;
  const int m0 = blockIdx.x*64;

  // staging: aggr_row = hbn[gr] + sl (+lo at atom 0) + sum of msg rows offsets[gr]..offsets[gr+1]
  for(int p=0;p<2;p++){
    int row = p*32 + (t>>3);
    int gr  = m0 + row;
    int c0  = (t&7)*32;
    float acc[32];
    if(gr < N){
      const unsigned short* hp = hbn + (size_t)gr*HID + c0;
#pragma unroll
      for(int q=0;q<4;q++){
        union { uint4 v; unsigned short us[8]; } hv;
        hv.v = *(const uint4*)(hp + q*8);
#pragma unroll
        for(int x=0;x<8;x++) acc[q*8+x] = bf2f(hv.us[x]);
      }
#pragma unroll
      for(int k=0;k<32;k++) acc[k] += sl[c0+k];
      if(gr == 0){
#pragma unroll
        for(int k=0;k<32;k++) acc[k] += lo[c0+k];
      }
      int s    = offsets[gr];
      int send = offsets[gr+1];
      const unsigned short* mp = msg + (size_t)s*HID + c0;
      // 2-deep unroll: 8 loads in flight per thread
      for(; s+1 < send; s += 2, mp += 2*HID){
        union { uint4 v; unsigned short us[8]; } m0v[4], m1v[4];
#pragma unroll
        for(int q=0;q<4;q++) m0v[q].v = *(const uint4*)(mp + q*8);
#pragma unroll
        for(int q=0;q<4;q++) m1v[q].v = *(const uint4*)(mp + HID + q*8);
#pragma unroll
        for(int q=0;q<4;q++)
#pragma unroll
          for(int x=0;x<8;x++) acc[q*8+x] += bf2f(m0v[q].us[x]) + bf2f(m1v[q].us[x]);
      }
      if(s < send){
        union { uint4 v; unsigned short us[8]; } mv[4];
#pragma unroll
        for(int q=0;q<4;q++) mv[q].v = *(const uint4*)(mp + q*8);
#pragma unroll
        for(int q=0;q<4;q++)
#pragma unroll
          for(int x=0;x<8;x++) acc[q*8+x] += bf2f(mv[q].us[x]);
      }
    } else {
#pragma unroll
      for(int k=0;k<32;k++) acc[k] = 0.f;
    }
#pragma unroll
    for(int q=0;q<4;q++){
      union { uint4 v; unsigned short us[8]; } pk;
#pragma unroll
      for(int x=0;x<8;x++) pk.us[x] = f2bf(acc[q*8+x]);
      *(uint4*)((char*)sA + swzb(row, (c0+q*8)*2, 512)) = pk.v;
    }
  }
  __syncthreads();

  const int w = t>>6, l = t&63, lg = l>>4, lc = l&15;
  const f32x4 z4 = {0.f,0.f,0.f,0.f};
  f32x4 zacc[4][4];
#pragma unroll
  for(int fi=0;fi<4;fi++)
#pragma unroll
    for(int fj=0;fj<4;fj++) zacc[fi][fj] = z4;

  for(int c=0;c<4;c++){
    f32x4 h1[4][2];
#pragma unroll
    for(int fi=0;fi<4;fi++){ h1[fi][0] = z4; h1[fi][1] = z4; }
    for(int k0=0;k0<256;k0+=32){
      bf16x8 a[4];
#pragma unroll
      for(int fi=0;fi<4;fi++)
        a[fi] = *(const bf16x8*)((const char*)sA + swzb(fi*16+lc, (k0+lg*8)*2, 512));
#pragma unroll
      for(int fj=0;fj<2;fj++){
        int col = c*128 + w*32 + fj*16 + lc;
        bf16x8 b = *(const bf16x8*)(m1T + (size_t)col*256 + k0 + lg*8);
#pragma unroll
        for(int fi=0;fi<4;fi++)
          h1[fi][fj] = mfma16(a[fi], b, h1[fi][fj]);
      }
    }
    __syncthreads();
#pragma unroll
    for(int fj=0;fj<2;fj++){
      int col  = c*128 + w*32 + fj*16 + lc;
      int lcol = w*32 + fj*16 + lc;
      float bias = b1[col];
#pragma unroll
      for(int fi=0;fi<4;fi++)
#pragma unroll
        for(int r=0;r<4;r++){
          int row = fi*16 + lg*4 + r;
          float v = h1[fi][fj][r] + bias;
          v = v > 0.f ? v : 0.f;
          *(unsigned short*)((char*)sHD + swzb(row, lcol*2, 256)) = f2bf(v);
        }
    }
    __syncthreads();
    for(int k0=0;k0<128;k0+=32){
      bf16x8 a[4], b[4];
#pragma unroll
      for(int fi=0;fi<4;fi++)
        a[fi] = *(const bf16x8*)((const char*)sHD + swzb(fi*16+lc, (k0+lg*8)*2, 256));
#pragma unroll
      for(int fj=0;fj<4;fj++){
        int col = w*64 + fj*16 + lc;
        b[fj] = *(const bf16x8*)(m2T + (size_t)col*512 + c*128 + k0 + lg*8);
      }
#pragma unroll
      for(int fi=0;fi<4;fi++)
#pragma unroll
        for(int fj=0;fj<4;fj++)
          zacc[fi][fj] = mfma16(a[fi], b[fj], zacc[fi][fj]);
    }
  }

#pragma unroll
  for(int fj=0;fj<4;fj++){
    int col = w*64 + fj*16 + lc;
    float bias = b2[col];
    float s1 = 0.f, s2 = 0.f;
#pragma unroll
    for(int fi=0;fi<4;fi++)
#pragma unroll
      for(int r=0;r<4;r++){
        int gr = m0 + fi*16 + lg*4 + r;
        float v = zacc[fi][fj][r] + bias;
        if(gr < N){
          z[(size_t)gr*HID + col] = v;
          s1 += v; s2 += v*v;
        }
      }
    s1 += __shfl_xor(s1, 16, 64); s1 += __shfl_xor(s1, 32, 64);
    s2 += __shfl_xor(s2, 16, 64); s2 += __shfl_xor(s2, 32, 64);
    if(lg == 0){
      atomicAdd(&stats[col],       s1);
      atomicAdd(&stats[HID + col], s2);
    }
  }
}

__global__ void stats_fin(const float* __restrict__ stats, float* __restrict__ musig, float invN){
  int c = threadIdx.x;
  float mu  = stats[c] * invN;
  float var = stats[HID + c] * invN - mu*mu;
  musig[c]       = mu;
  musig[HID + c] = rsqrtf(var + BN_EPS);
}

__global__ void final_bn(float* __restrict__ out, const float* __restrict__ musig,
                         const float* __restrict__ gamma, const float* __restrict__ beta,
                         long total4){
  for(long i = (long)blockIdx.x*blockDim.x + threadIdx.x; i < total4; i += (long)gridDim.x*blockDim.x){
    int c0 = ((int)(i & 63)) << 2;
    float4 v = ((const float4*)out)[i];
    float o[4] = {v.x, v.y, v.z, v.w};
#pragma unroll
    for(int c=0;c<4;c++)
      o[c] = gamma[c0+c]*(o[c] - musig[c0+c])*musig[256+c0+c] + beta[c0+c];
    float4 ov = {o[0], o[1], o[2], o[3]};
    ((float4*)out)[i] = ov;
  }
}

// ---------------- host ----------------

extern "C" void kernel_launch(void* const* d_in, const int* in_sizes, int n_in,
                              void* d_out, int out_size, void* d_ws, size_t ws_size,
                              hipStream_t stream)
{
  const float* f_atoms = (const float*)d_in[0];
  const float* f_bonds = (const float*)d_in[1];
  const int*   a2b     = (const int*)d_in[2];
  const int*   b2a     = (const int*)d_in[3];
  const float* w_atom  = (const float*)d_in[6];
  const float* wb_w1   = (const float*)d_in[7];
  const float* wb_b1   = (const float*)d_in[8];
  const float* wb_w2   = (const float*)d_in[9];
  const float* wb_b2   = (const float*)d_in[10];
  const float* mlp_w1  = (const float*)d_in[11];
  const float* mlp_b1  = (const float*)d_in[12];
  const float* mlp_w2  = (const float*)d_in[13];
  const float* mlp_b2  = (const float*)d_in[14];
  const float* bn_g    = (const float*)d_in[15];
  const float* bn_b    = (const float*)d_in[16];
  const int N = in_sizes[0] / AFD;
  const int E = in_sizes[3];
  float* out = (float*)d_out;
  (void)n_in; (void)out_size; (void)ws_size;

  char* ws = (char*)d_ws;
  size_t off = 0;
  auto alloc = [&](size_t bytes)->char* {
    char* p = ws + off; off += (bytes + 255) & ~(size_t)255; return p;
  };
  float* hbuf          = (float*)alloc((size_t)N*HID*4);
  unsigned short* hbn  = (unsigned short*)alloc((size_t)N*HID*2);
  unsigned short* msg  = (unsigned short*)alloc((size_t)E*HID*2);
  unsigned short* eb   = (unsigned short*)alloc((size_t)E*16*2);
  int* b2slot          = (int*)alloc((size_t)E*4);
  int* offsets         = (int*)alloc((size_t)(N+1)*4);
  int* offs_local      = (int*)alloc((size_t)N*4);
  int* partials        = (int*)alloc((size_t)512*4);
  int* total           = (int*)alloc((size_t)4);
  unsigned short* wAT  = (unsigned short*)alloc((size_t)HID*KA_PAD*2);
  unsigned short* w1T  = (unsigned short*)alloc((size_t)3*HID*KB_PAD*2);
  unsigned short* w2T  = (unsigned short*)alloc((size_t)3*HID*HID*2);
  unsigned short* m1T  = (unsigned short*)alloc((size_t)3*512*HID*2);
  unsigned short* m2T  = (unsigned short*)alloc((size_t)3*HID*512*2);
  float* sl            = (float*)alloc((size_t)3*HID*4);
  float* stats         = (float*)alloc((size_t)3*512*4);
  float* musig         = (float*)alloc((size_t)3*512*4);
  float* lo            = (float*)alloc((size_t)3*HID*4);

  hipMemsetAsync(stats,  0,    (size_t)3*512*4, stream);
  hipMemsetAsync(lo,     0,    (size_t)3*HID*4, stream);
  hipMemsetAsync(b2slot, 0xFF, (size_t)E*4, stream);

  auto cdiv = [](long a, long b){ return (int)((a + b - 1)/b); };
  const int nb = cdiv(N, 256);

  // CSR slot map
  count_scan<<<nb,256,0,stream>>>(a2b, offs_local, partials, N);
  scan_partials<<<1,512,0,stream>>>(partials, nb, total);
  add_base<<<512,256,0,stream>>>(offs_local, partials, total, offsets, N);
  build_slot<<<2048,256,0,stream>>>(a2b, offsets, b2slot, N);

  pack_wT<<<cdiv((long)HID*KA_PAD,256),256,0,stream>>>(w_atom, wAT, AFD, HID, KA_PAD);
  for(int l=0;l<3;l++){
    pack_wT<<<cdiv((long)HID*KB_PAD,256),256,0,stream>>>(wb_w1 + (size_t)l*16*HID,  w1T + (size_t)l*HID*KB_PAD, 16,  HID, KB_PAD);
    pack_wT<<<cdiv((long)HID*HID,256),256,0,stream>>>(wb_w2 + (size_t)l*HID*HID,  w2T + (size_t)l*HID*HID,  HID, HID, HID);
    pack_wT<<<cdiv((long)512*HID,256),256,0,stream>>>(mlp_w1 + (size_t)l*HID*512, m1T + (size_t)l*512*HID,  HID, 512, HID);
    pack_wT<<<cdiv((long)HID*512,256),256,0,stream>>>(mlp_w2 + (size_t)l*512*HID, m2T + (size_t)l*HID*512,  512, HID, 512);
  }
  pack_eb<<<2048,256,0,stream>>>(f_bonds, eb, E);
  sl_emb_kernel<<<3,256,0,stream>>>(wb_w1, wb_b1, wb_w2, wb_b2, sl);

  atom_embed<<<cdiv(N,64),256,0,stream>>>(f_atoms, wAT, hbuf, N);

  float* hraw = hbuf;
  float* zdst = out;
  for(int l=0;l<3;l++){
    int applyBN = (l > 0);
    const float* ms = applyBN ? (musig + (size_t)(l-1)*512) : musig;
    const float* gp = applyBN ? (bn_g + (size_t)(l-1)*HID)  : bn_g;
    const float* bp = applyBN ? (bn_b + (size_t)(l-1)*HID)  : bn_b;
    bn_relu_pack<<<2048,256,0,stream>>>(hraw, ms, gp, bp, applyBN, hbn, (long)N*32);
    edge_mlp_msg<<<cdiv(E,64),256,0,stream>>>(eb,
        w1T + (size_t)l*HID*KB_PAD, wb_b1 + (size_t)l*HID,
        w2T + (size_t)l*HID*HID,    wb_b2 + (size_t)l*HID,
        b2a, b2slot, hbn, msg, lo + (size_t)l*HID, E);
    node_mlp_fused<<<cdiv(N,64),256,0,stream>>>(msg, offsets, hbn,
        sl + (size_t)l*HID, lo + (size_t)l*HID,
        m1T + (size_t)l*512*HID, mlp_b1 + (size_t)l*512,
        m2T + (size_t)l*HID*512, mlp_b2 + (size_t)l*HID,
        zdst, stats + (size_t)l*512, N);
    stats_fin<<<1,256,0,stream>>>(stats + (size_t)l*512, musig + (size_t)l*512, 1.0f/(float)N);
    float* tmp = hraw; hraw = zdst; zdst = tmp;
  }
  final_bn<<<2048,256,0,stream>>>(out, musig + 2*512, bn_g + 2*HID, bn_b + 2*HID, (long)N*64);
}